// Round 2
// 256.080 us; speedup vs baseline: 1.0747x; 1.0747x over previous
//
#include <hip/hip_runtime.h>

typedef unsigned short u16;
typedef short bf16x8 __attribute__((ext_vector_type(8)));
typedef float f32x4 __attribute__((ext_vector_type(4)));

typedef __attribute__((address_space(3))) unsigned int lds_uint;
typedef __attribute__((address_space(1))) const unsigned int glob_uint;

__device__ __forceinline__ void gll16(const void* g, void* l) {
    __builtin_amdgcn_global_load_lds((glob_uint*)g, (lds_uint*)l, 16, 0, 0);
}

__device__ __forceinline__ u16 f2b(float f) {
    union { float f; unsigned int u; } cv; cv.f = f;
    unsigned int u = cv.u;
    u += 0x7fffu + ((u >> 16) & 1u);
    return (u16)(u >> 16);
}

__device__ __forceinline__ uint2 pack4(float a, float b, float c, float d) {
    uint2 r;
    r.x = (unsigned int)f2b(a) | ((unsigned int)f2b(b) << 16);
    r.y = (unsigned int)f2b(c) | ((unsigned int)f2b(d) << 16);
    return r;
}

// ---------------- prep: head-major weight reorder + bf16 convert ----------------
// wqkvh[(h*192+j)][k] : j in [0,64)=Q, [64,128)=K, [128,192)=V (output dim j&63)
// woT[n][k] = wo[k][n]; biash[h*192+j]
__global__ void prep_kernel(const float* __restrict__ wq, const float* __restrict__ wk,
                            const float* __restrict__ wv, const float* __restrict__ wo,
                            const float* __restrict__ bq, const float* __restrict__ bk,
                            const float* __restrict__ bv,
                            u16* __restrict__ wqkvh, u16* __restrict__ woT,
                            float* __restrict__ biash) {
    int idx = blockIdx.x * 256 + threadIdx.x;
    const int N1 = 512 * 1536;
    const int N2 = 512 * 512;
    if (idx < N1) {
        int k = idx / 1536, n2 = idx % 1536;
        int h = n2 / 192, j = n2 % 192;
        const float* w = (j < 64) ? wq : (j < 128) ? wk : wv;
        wqkvh[(size_t)n2 * 512 + k] = f2b(w[k * 512 + h * 64 + (j & 63)]);
    } else if (idx < N1 + N2) {
        int i = idx - N1;
        int k = i / 512, n = i % 512;
        woT[n * 512 + k] = f2b(wo[k * 512 + n]);
    } else if (idx < N1 + N2 + 1536) {
        int n2 = idx - N1 - N2;
        int h = n2 / 192, j = n2 % 192;
        const float* b = (j < 64) ? bq : (j < 128) ? bk : bv;
        biash[n2] = b[h * 64 + (j & 63)];
    }
}

// ---------------- pre: x fp32 -> bf16, window-shift permuted ----------------
__global__ __launch_bounds__(256) void pre_kernel(const float* __restrict__ x,
                                                  u16* __restrict__ xw) {
    int idx = blockIdx.x * 256 + threadIdx.x;      // 8 elems per thread
    int row = idx >> 6;
    int c = (idx & 63) * 8;
    int b_ = row >> 12, win = (row >> 6) & 63, t = row & 63;
    int wi = win >> 3, wj = win & 7, ti = t >> 3, tj = t & 7;
    int hh = (wi * 8 + ti + 4) & 63, ww = (wj * 8 + tj + 4) & 63;
    const float* src = x + ((size_t)b_ * 4096 + hh * 64 + ww) * 512 + c;
    float4 v0 = *(const float4*)src;
    float4 v1 = *(const float4*)(src + 4);
    ushort4 p0, p1;
    p0.x = f2b(v0.x); p0.y = f2b(v0.y); p0.z = f2b(v0.z); p0.w = f2b(v0.w);
    p1.x = f2b(v1.x); p1.y = f2b(v1.y); p1.z = f2b(v1.z); p1.w = f2b(v1.w);
    u16* dst = xw + (size_t)row * 512 + c;
    *(ushort4*)dst = p0;
    *(ushort4*)(dst + 4) = p1;
}

// ---------------- fused QKV + attention: one block per (window, head) ----------------
// Grid 4096: win = bid & 511, h = bid >> 9.  Stride-512 head mapping keeps all 8
// head-blocks of a window on the same XCD (512 % 8 == 0) for A-tile L2 locality.
// GEMM 64x192x512 (A=xw window rows, B=wqkvh head slab), epilogue writes Q,K
// (packed b64) and V^T into LDS *aliased over the dead staging region*, then
// attention, packed O stores to ows[tok][h*64+d].
// LDS map (u16 units): staging As[0,4096) Bs[4096,16384)
//                      after-GEMM alias: QKs@0 (64x136)  VT@8704 (64x72)
//                      Pw@13312 + wid*1152 (16x72, per-wave, no cross-wave use)
// Total 17920 u16 = 35840 B  ->  4 blocks/CU (vs 59392 B -> 2 blocks/CU before).
__global__ __launch_bounds__(256, 4) void fused_qkv_attn(const u16* __restrict__ xw,
        const u16* __restrict__ wqkvh, const float* __restrict__ biash,
        u16* __restrict__ ows) {
    __shared__ u16 S[17920];
    const int tid = threadIdx.x;
    const int lane = tid & 63, wid = tid >> 6;
    const int wr = wid >> 1, wc = wid & 1;
    const int m = lane & 15, qd = lane >> 4;
    const int win = blockIdx.x & 511;
    const int h = blockIdx.x >> 9;
    const int rowBase = win * 64;

    u16* As  = S;
    u16* Bs  = S + 4096;
    u16* QKs = S;                       // aliases As/Bs (staging dead at epilogue)
    u16* VT  = S + 8704;                // aliases Bs
    u16* Pw  = S + 13312 + wid * 1152;  // 16x72 per wave

    const u16* Bsrc = wqkvh + (size_t)h * 192 * 512;
    f32x4 acc[2][6];
#pragma unroll
    for (int i = 0; i < 2; ++i)
#pragma unroll
        for (int j = 0; j < 6; ++j) acc[i][j] = (f32x4){0.f, 0.f, 0.f, 0.f};

    for (int kt = 0; kt < 8; ++kt) {
        const int k0 = kt * 64;
#pragma unroll
        for (int j = 0; j < 2; ++j) {
            int q = j * 256 + tid;
            int r = q >> 3, c = (q & 7) ^ (r & 7);
            gll16(xw + (size_t)(rowBase + r) * 512 + k0 + c * 8, As + q * 8);
        }
#pragma unroll
        for (int j = 0; j < 6; ++j) {
            int q = j * 256 + tid;
            int r = q >> 3, c = (q & 7) ^ (r & 7);
            gll16(Bsrc + (size_t)r * 512 + k0 + c * 8, Bs + q * 8);
        }
        __syncthreads();                 // staging visible (vmcnt drained by compiler)
#pragma unroll
        for (int s = 0; s < 2; ++s) {
            bf16x8 a[2], b[6];
#pragma unroll
            for (int ni = 0; ni < 6; ++ni) {
                int R = wc * 96 + ni * 16 + m;
                b[ni] = *(const bf16x8*)&Bs[R * 64 + (((s * 4 + qd) ^ (R & 7)) * 8)];
            }
#pragma unroll
            for (int mi = 0; mi < 2; ++mi) {
                int R = wr * 32 + mi * 16 + m;
                a[mi] = *(const bf16x8*)&As[R * 64 + (((s * 4 + qd) ^ (R & 7)) * 8)];
            }
            // swapped: D[row=out-dim local qd*4+rr][col=token local m]
#pragma unroll
            for (int mi = 0; mi < 2; ++mi)
#pragma unroll
                for (int ni = 0; ni < 6; ++ni)
                    acc[mi][ni] = __builtin_amdgcn_mfma_f32_16x16x32_bf16(b[ni], a[mi], acc[mi][ni], 0, 0, 0);
        }
        __syncthreads();                 // all MFMA reads done before restage/epilogue
    }

    // epilogue: Q,K -> QKs[t][0..127]; V -> VT[d][t]   (writes alias dead staging)
#pragma unroll
    for (int mi = 0; mi < 2; ++mi) {
        int t = wr * 32 + mi * 16 + m;
#pragma unroll
        for (int ni = 0; ni < 6; ++ni) {
            int cn = wc * 96 + ni * 16;
            float4 bb = *(const float4*)&biash[h * 192 + cn + qd * 4];
            if (cn < 128) {
                *(uint2*)&QKs[t * 136 + cn + qd * 4] =
                    pack4(acc[mi][ni][0] + bb.x, acc[mi][ni][1] + bb.y,
                          acc[mi][ni][2] + bb.z, acc[mi][ni][3] + bb.w);
            } else {
                int d0 = cn - 128 + qd * 4;
                VT[(d0 + 0) * 72 + t] = f2b(acc[mi][ni][0] + bb.x);
                VT[(d0 + 1) * 72 + t] = f2b(acc[mi][ni][1] + bb.y);
                VT[(d0 + 2) * 72 + t] = f2b(acc[mi][ni][2] + bb.z);
                VT[(d0 + 3) * 72 + t] = f2b(acc[mi][ni][3] + bb.w);
            }
        }
    }
    __syncthreads();

    // ---- attention: wave handles S rows q0..q0+15 ----
    const int q0 = wid * 16;
    f32x4 sa[4];
#pragma unroll
    for (int ni = 0; ni < 4; ++ni) sa[ni] = (f32x4){0.f, 0.f, 0.f, 0.f};
#pragma unroll
    for (int s = 0; s < 2; ++s) {
        bf16x8 qf = *(const bf16x8*)&QKs[(q0 + m) * 136 + s * 32 + qd * 8];
#pragma unroll
        for (int ni = 0; ni < 4; ++ni) {
            bf16x8 kf = *(const bf16x8*)&QKs[(ni * 16 + m) * 136 + 64 + s * 32 + qd * 8];
            sa[ni] = __builtin_amdgcn_mfma_f32_16x16x32_bf16(qf, kf, sa[ni], 0, 0, 0);
        }
    }
    const float c1 = 0.125f * 1.4426950408889634f;
#pragma unroll
    for (int rr = 0; rr < 4; ++rr) {
        float mx = -3.4e38f;
#pragma unroll
        for (int ni = 0; ni < 4; ++ni) mx = fmaxf(mx, sa[ni][rr]);
        mx = fmaxf(mx, __shfl_xor(mx, 1, 64));
        mx = fmaxf(mx, __shfl_xor(mx, 2, 64));
        mx = fmaxf(mx, __shfl_xor(mx, 4, 64));
        mx = fmaxf(mx, __shfl_xor(mx, 8, 64));
        float sum = 0.f;
#pragma unroll
        for (int ni = 0; ni < 4; ++ni) {
            float p = exp2f((sa[ni][rr] - mx) * c1);
            sa[ni][rr] = p;
            sum += p;
        }
        sum += __shfl_xor(sum, 1, 64);
        sum += __shfl_xor(sum, 2, 64);
        sum += __shfl_xor(sum, 4, 64);
        sum += __shfl_xor(sum, 8, 64);
        float inv = 1.f / sum;
        int r = qd * 4 + rr;
#pragma unroll
        for (int ni = 0; ni < 4; ++ni)
            Pw[r * 72 + ni * 16 + m] = f2b(sa[ni][rr] * inv);
    }

    f32x4 oa[4];
#pragma unroll
    for (int ni = 0; ni < 4; ++ni) oa[ni] = (f32x4){0.f, 0.f, 0.f, 0.f};
#pragma unroll
    for (int s = 0; s < 2; ++s) {
        bf16x8 pf = *(const bf16x8*)&Pw[m * 72 + s * 32 + qd * 8];
#pragma unroll
        for (int ni = 0; ni < 4; ++ni) {
            bf16x8 vf = *(const bf16x8*)&VT[(ni * 16 + m) * 72 + s * 32 + qd * 8];
            // swapped: D[row=d local][col=q-token local]
            oa[ni] = __builtin_amdgcn_mfma_f32_16x16x32_bf16(vf, pf, oa[ni], 0, 0, 0);
        }
    }
    u16* dst = ows + (size_t)(rowBase + q0 + m) * 512 + h * 64;
#pragma unroll
    for (int ni = 0; ni < 4; ++ni)
        *(uint2*)&dst[ni * 16 + qd * 4] =
            pack4(oa[ni][0], oa[ni][1], oa[ni][2], oa[ni][3]);
}

// ---------------- proj GEMM: M=32768 N=512 K=512, BK=64, swapped epilogue ----------------
__global__ __launch_bounds__(256) void proj_gemm(const u16* __restrict__ ows,
        const u16* __restrict__ woT, const float* __restrict__ bo,
        const float* __restrict__ x, float* __restrict__ out) {
    __shared__ u16 As[128 * 64];
    __shared__ u16 Bs[128 * 64];
    const int tid = threadIdx.x;
    const int lane = tid & 63, wid = tid >> 6;
    const int wr = wid >> 1, wc = wid & 1;
    const int m = lane & 15, qd = lane >> 4;
    const int rowBase = blockIdx.y * 128;
    const int colBase = blockIdx.x * 128;
    const int c8 = (lane & 7) ^ (lane >> 3);

    f32x4 acc[4][4];
#pragma unroll
    for (int i = 0; i < 4; ++i)
#pragma unroll
        for (int j = 0; j < 4; ++j) acc[i][j] = (f32x4){0.f, 0.f, 0.f, 0.f};

    for (int kt = 0; kt < 8; ++kt) {
        const int k0 = kt * 64;
        __syncthreads();
#pragma unroll
        for (int j = 0; j < 4; ++j) {
            int q = (j * 4 + wid) * 64 + lane;
            int r = (j * 4 + wid) * 8 + (lane >> 3);
            gll16(ows + (size_t)(rowBase + r) * 512 + k0 + c8 * 8, &As[q * 8]);
            gll16(woT + (size_t)(colBase + r) * 512 + k0 + c8 * 8, &Bs[q * 8]);
        }
        __syncthreads();
#pragma unroll
        for (int s = 0; s < 2; ++s) {
            bf16x8 a[4], b[4];
#pragma unroll
            for (int ni = 0; ni < 4; ++ni) {
                int R = wc * 64 + ni * 16 + m;
                b[ni] = *(const bf16x8*)&Bs[R * 64 + (((s * 4 + qd) ^ (R & 7)) * 8)];
            }
#pragma unroll
            for (int mi = 0; mi < 4; ++mi) {
                int R = wr * 64 + mi * 16 + m;
                a[mi] = *(const bf16x8*)&As[R * 64 + (((s * 4 + qd) ^ (R & 7)) * 8)];
            }
            // swapped: D[row=col-dim local][col=token local]
#pragma unroll
            for (int mi = 0; mi < 4; ++mi)
#pragma unroll
                for (int ni = 0; ni < 4; ++ni)
                    acc[mi][ni] = __builtin_amdgcn_mfma_f32_16x16x32_bf16(b[ni], a[mi], acc[mi][ni], 0, 0, 0);
        }
    }

#pragma unroll
    for (int mi = 0; mi < 4; ++mi) {
        int row = rowBase + wr * 64 + mi * 16 + m;    // win*64 + t
        int win = row >> 6, t = row & 63;
        int b_ = win >> 6, wh = (win >> 3) & 7, ww_ = win & 7;
        int ti = t >> 3, tj = t & 7;
        int hh = (wh * 8 + ti + 4) & 63;
        int www = (ww_ * 8 + tj + 4) & 63;
        size_t tok = (size_t)b_ * 4096 + hh * 64 + www;
#pragma unroll
        for (int ni = 0; ni < 4; ++ni) {
            int col0 = colBase + wc * 64 + ni * 16 + qd * 4;
            float4 xv = *(const float4*)&x[tok * 512 + col0];
            float4 bv = *(const float4*)&bo[col0];
            float4 o;
            o.x = acc[mi][ni][0] + bv.x + xv.x;
            o.y = acc[mi][ni][1] + bv.y + xv.y;
            o.z = acc[mi][ni][2] + bv.z + xv.z;
            o.w = acc[mi][ni][3] + bv.w + xv.w;
            *(float4*)&out[tok * 512 + col0] = o;
        }
    }
}

extern "C" void kernel_launch(void* const* d_in, const int* in_sizes, int n_in,
                              void* d_out, int out_size, void* d_ws, size_t ws_size,
                              hipStream_t stream) {
    const float* x  = (const float*)d_in[0];
    const float* wq = (const float*)d_in[1];
    const float* bq = (const float*)d_in[2];
    const float* wk = (const float*)d_in[3];
    const float* bk = (const float*)d_in[4];
    const float* wv = (const float*)d_in[5];
    const float* bv = (const float*)d_in[6];
    const float* wo = (const float*)d_in[7];
    const float* bo = (const float*)d_in[8];
    float* out = (float*)d_out;
    char* ws = (char*)d_ws;

    u16*   wqkvh = (u16*)ws;                               // 1536*512*2
    u16*   woT   = (u16*)(ws + 1572864);                   // 512*512*2
    float* biash = (float*)(ws + 1572864 + 524288);        // 1536*4
    size_t off = 2103296;
    u16* xw  = (u16*)(ws + off);                           // 32768*512 u16 = 32 MiB
    u16* ows = xw + (size_t)16777216;                      // 32768*512 u16 = 32 MiB

    const int prepN = 512 * 1536 + 512 * 512 + 1536;
    prep_kernel<<<dim3((prepN + 255) / 256), dim3(256), 0, stream>>>(
        wq, wk, wv, wo, bq, bk, bv, wqkvh, woT, biash);
    pre_kernel<<<dim3(8192), dim3(256), 0, stream>>>(x, xw);
    fused_qkv_attn<<<dim3(4096), dim3(256), 0, stream>>>(xw, wqkvh, biash, ows);
    proj_gemm<<<dim3(4, 256), dim3(256), 0, stream>>>(ows, woT, bo, x, out);
}